// Round 6
// baseline (327.379 us; speedup 1.0000x reference)
//
#include <hip/hip_runtime.h>

// Fused attention block: q/k/v = relu(X W + b); A = softmax(qk^T/sqrt(C)); out = relu((A v) FC + b)
// B=8, Lq=Lk=2048, C1=C=512.  bf16 16x16x32 MFMA, fp32 accumulate.
// R13 == R12 resubmitted verbatim (R5 bench was a GPUAcquisitionTimeout; kernel unmeasured).
// R11->R12: (1) qkvf grid reverted to R3's 3D decode (R4's batch-per-XCD grouping
// thrashed the 4MB L2: FETCH halved but dur 77->86us).  (2) qkvf A-operand now goes
// global->register directly (fragment row segments are 64B-contiguous, L2-resident),
// ping-pong prefetched 1 iter ahead; only B is LDS-staged (ring-3, 8KB/slot).  LDS
// traffic/iter halves 48->24KB (was ~45% of kernel time).  vmcnt invariant: enter iter
// with [B(t+1)x2] in flight; issue [A(t+1)x4, B(t+2)x2]; VMC(2) at bottom.
// Swizzle fix from R11 kept.  proj/pvf/prep2 unchanged.

typedef __attribute__((ext_vector_type(8))) short short8;  // 8 bf16 (4 VGPRs)
typedef __attribute__((ext_vector_type(4))) float f32x4;

#define SEQ 2048
#define CH 512
#define NB 8
#define MTOT (NB * SEQ)   // 16384

// async global->LDS, 16B/lane; LDS dest = wave-uniform base + lane*16 (m104/m108)
#define GLDS16(gp, lp)                                                                  \
  __builtin_amdgcn_global_load_lds((const __attribute__((address_space(1))) void*)(gp), \
                                   (__attribute__((address_space(3))) void*)(lp), 16, 0, 0)

__device__ __forceinline__ unsigned short f2bf(float f) {  // fp32 -> bf16 RNE
  unsigned u = __float_as_uint(f);
  u += 0x7fffu + ((u >> 16) & 1u);
  return (unsigned short)(u >> 16);
}

// pack two fp32 -> (bf16(hi)<<16)|bf16(lo) by truncation: one v_perm_b32
__device__ __forceinline__ unsigned pack2bf(float lo, float hi) {
  return __builtin_amdgcn_perm(__float_as_uint(hi), __float_as_uint(lo), 0x07060302u);
}

#define CFENCE asm volatile("" ::: "memory")
#define SB0 __builtin_amdgcn_sched_barrier(0)
#define BAR8                          \
  do {                                \
    CFENCE;                           \
    __builtin_amdgcn_s_barrier();     \
    SB0;                              \
  } while (0)
#define VMC(n)                                              \
  do {                                                      \
    asm volatile("s_waitcnt vmcnt(" #n ")" ::: "memory");   \
    SB0;                                                    \
  } while (0)
#define LGKM0                                            \
  do {                                                   \
    asm volatile("s_waitcnt lgkmcnt(0)" ::: "memory");   \
    SB0;                                                 \
  } while (0)

// ---------------- prep2: wtrans x4 + biasKV + rowsum zero (273 blocks) ----------------
__global__ __launch_bounds__(256) void prep2_kernel(
    const float* __restrict__ W0, const float* __restrict__ W1,
    const float* __restrict__ W2, const float* __restrict__ W3,
    unsigned short* __restrict__ Wt,
    const float* __restrict__ Wk_b, const float* __restrict__ Wv_b,
    float* __restrict__ biasKV, float* __restrict__ rowsum) {
  __shared__ __attribute__((aligned(16))) unsigned short tile[64 * 72];
  const int blk = blockIdx.x;
  const int t = threadIdx.x;
  if (blk < 256) {
    const int z = blk >> 6;
    const int bx = blk & 7, by = (blk >> 3) & 7;
    const float* W = (z == 0) ? W0 : (z == 1) ? W1 : (z == 2) ? W2 : W3;
    unsigned short* Wtz = Wt + (long)z * 512 * 512;
    const int k0 = by * 64, n0 = bx * 64;
    const int r = t >> 4, cq = (t & 15) * 4;
#pragma unroll
    for (int j = 0; j < 4; ++j) {
      int row = r + 16 * j;  // k index
      float4 v = *(const float4*)&W[(long)(k0 + row) * 512 + n0 + cq];
      tile[row * 72 + cq + 0] = f2bf(v.x);
      tile[row * 72 + cq + 1] = f2bf(v.y);
      tile[row * 72 + cq + 2] = f2bf(v.z);
      tile[row * 72 + cq + 3] = f2bf(v.w);
    }
    __syncthreads();
#pragma unroll
    for (int j = 0; j < 4; ++j) {
      int row = r + 16 * j;  // n index
      ushort4 o;
      o.x = tile[(cq + 0) * 72 + row];
      o.y = tile[(cq + 1) * 72 + row];
      o.z = tile[(cq + 2) * 72 + row];
      o.w = tile[(cq + 3) * 72 + row];
      *(ushort4*)&Wtz[(long)(n0 + row) * 512 + k0 + cq] = o;
    }
  } else if (blk == 256) {
    biasKV[t] = Wk_b[t];
    biasKV[t + 256] = Wk_b[t + 256];
    biasKV[t + 512] = Wv_b[t];
    biasKV[t + 768] = Wv_b[t + 256];
  } else {
    const int zb = blk - 257;  // 0..15
    f32x4 z4 = {0.f, 0.f, 0.f, 0.f};
    *(f32x4*)&rowsum[(zb * 256 + t) * 4] = z4;
  }
}

// ---------------- proj body: A fp32 [M][512], Bt bf16 [N][512], 128x128 tile, BK=32 ----
// out = relu(A.Bt^T + bias) -> bf16.  3-slot ring (24KB/slot, 72KB), stage t+2 early,
// vmcnt(6) counted, 1 barrier/iter.
template <int LDO>
__device__ __forceinline__ void proj_body(const float* __restrict__ A,
                                          const unsigned short* __restrict__ Bt,
                                          const float* __restrict__ bias,
                                          unsigned short* __restrict__ Op,
                                          long m0, long n0, unsigned short* smem) {
  const int t = threadIdx.x;
  const int w = t >> 6, l = t & 63;
  const int wr = w >> 1, wc = w & 1;
  const int lr = l & 15, lg = l >> 4;
  // A staging: 8 lanes/row (4 floats each), src chunk = (l&7)^(l>>3) [= c0 ^ row&7]
  const float* ga = A + (m0 + 32 * w + (l >> 3)) * CH + ((l & 7) ^ (l >> 3)) * 4;
  // B staging: 4 lanes/row (8 bf16 each), src chunk = (l&3)^((l>>3)&3) [= c0 ^ (row>>1)&3]
  const unsigned short* gb =
      Bt + (n0 + 32 * w + (l >> 2)) * CH + (((l & 3) ^ ((l >> 3) & 3)) * 8);

  auto stage = [&](int c, int kt) {  // 6 glds issues: A 16KB + B 8KB
    float* Ac = (float*)(smem + (long)c * 12288);
    unsigned short* Bc = smem + (long)c * 12288 + 8192;
#pragma unroll
    for (int j = 0; j < 4; ++j)
      GLDS16(ga + (long)8 * j * CH + kt * 32, Ac + (32 * w + 8 * j) * 32);
    GLDS16(gb + kt * 32, Bc + 32 * w * 32);
    GLDS16(gb + (long)16 * CH + kt * 32, Bc + (32 * w + 16) * 32);
  };

  f32x4 acc[4][4] = {};
  constexpr int NT = CH / 32;  // 16
  stage(0, 0); stage(1, 1);
  VMC(6);
  BAR8;
#pragma unroll
  for (int kt = 0; kt < NT; ++kt) {
    const int c = kt % 3;
    if (kt + 2 < NT) stage((kt + 2) % 3, kt + 2);
    const float* Ac = (const float*)(smem + (long)c * 12288);
    const unsigned short* Bc = smem + (long)c * 12288 + 8192;
    short8 af[4], bfr[4];
#pragma unroll
    for (int i = 0; i < 4; ++i) {
      const int row = 64 * wr + 16 * i + lr;
      f32x4 a0 = *(f32x4*)&Ac[row * 32 + ((2 * lg) ^ (lr & 7)) * 4];
      f32x4 a1 = *(f32x4*)&Ac[row * 32 + ((2 * lg + 1) ^ (lr & 7)) * 4];
      union { unsigned u[4]; short8 s; } pk;
      pk.u[0] = pack2bf(a0[0], a0[1]);
      pk.u[1] = pack2bf(a0[2], a0[3]);
      pk.u[2] = pack2bf(a1[0], a1[1]);
      pk.u[3] = pack2bf(a1[2], a1[3]);
      af[i] = pk.s;
      bfr[i] = *(short8*)&Bc[(64 * wc + 16 * i + lr) * 32 + (lg ^ ((lr >> 1) & 3)) * 8];
    }
#pragma unroll
    for (int mi = 0; mi < 4; ++mi)
#pragma unroll
      for (int ni = 0; ni < 4; ++ni)
        acc[mi][ni] =
            __builtin_amdgcn_mfma_f32_16x16x32_bf16(af[mi], bfr[ni], acc[mi][ni], 0, 0, 0);
    if (kt + 2 < NT) { VMC(6); } else if (kt + 1 < NT) { VMC(0); }
    BAR8;
  }
  // epilogue: relu(+bias) -> bf16 via [128][128] XOR-chunked patch (32KB)
  unsigned short* patch = smem;
  float bv[4];
#pragma unroll
  for (int ni = 0; ni < 4; ++ni) bv[ni] = bias[n0 + 64 * wc + 16 * ni + lr];
#pragma unroll
  for (int mi = 0; mi < 4; ++mi)
#pragma unroll
    for (int ni = 0; ni < 4; ++ni)
#pragma unroll
      for (int r = 0; r < 4; ++r) {
        const int m = 64 * wr + 16 * mi + 4 * lg + r;
        const int n = 64 * wc + 16 * ni + lr;
        patch[m * 128 + ((n >> 3) ^ (m & 15)) * 8 + (n & 7)] =
            f2bf(fmaxf(acc[mi][ni][r] + bv[ni], 0.0f));
      }
  __syncthreads();
  const int q = t & 3;
#pragma unroll
  for (int p = 0; p < 2; ++p) {
    const int m = 64 * p + (t >> 2);
#pragma unroll
    for (int i = 0; i < 4; ++i) {
      const int cc = i * 4 + q;  // 4 consecutive lanes -> 64B line
      short8 x = *(short8*)&patch[m * 128 + ((cc ^ (m & 15)) * 8)];
      *(short8*)&Op[(m0 + m) * LDO + n0 + cc * 8] = x;
    }
  }
}

// Q = relu(rep Wq + b) [x<4]; KV = relu(rep1 [Wk|Wv] + b) [x>=4]
// 1D grid 1536, XCD-grouped: xcd = bid&7 owns 16 m-panels; the 12 n-blocks of one
// m-panel are spaced 8 apart in bid -> same XCD, co-dispatched.
__global__ __launch_bounds__(256) void proj_kernel(const float* __restrict__ rep,
                                                   const float* __restrict__ rep1,
                                                   const unsigned short* __restrict__ Wt,
                                                   const float* __restrict__ Wq_b,
                                                   const float* __restrict__ biasKV,
                                                   unsigned short* __restrict__ Qb,
                                                   unsigned short* __restrict__ KVb) {
  __shared__ __attribute__((aligned(16))) unsigned short smem[36864];  // 72KB (3x24KB ring)
  const int bid = blockIdx.x;
  const int xcd = bid & 7, j = bid >> 3;   // j 0..191
  const int mp = j / 12, x = j % 12;       // mp 0..15
  const long m0 = (long)(xcd * 16 + mp) * 128;
  if (x < 4)
    proj_body<CH>(rep, Wt, Wq_b, Qb, m0, (long)x * 128, smem);
  else
    proj_body<1024>(rep1, Wt + 512 * 512, biasKV, KVb, m0, (long)(x - 4) * 128, smem);
}

// ---------------- qkvf NT GEMM body, 128x128 tile, BK=32, A-direct + B ring-3 ----------
// EPI 6: acc -> bf16                        (VFt)
// EPI 2: exp2(acc*scale) -> bf16 P, rowsum[m] += sum_n p   (QK^T)
// A: global->reg, 1 dwordx4 per fragment (row = 64wr+16i+lr, k = 8lg), ping-pong
// prefetch 1 iter ahead (af[2][4], compile-time indexed).  B: ring-3 LDS (8KB/slot),
// staged 2 iters ahead, XOR (row>>1)&3 swizzle.  vmcnt invariant at iter top:
// [B(t+1)x2] outstanding; issue [A(t+1)x4 ; B(t+2)x2]; VMC(2) after MFMA.
template <int EPI, int LDA, int LDB, int LDO, int K>
__device__ __forceinline__ void gemm_body32(const unsigned short* __restrict__ A,
                                            const unsigned short* __restrict__ Bt,
                                            float* __restrict__ rowsum,
                                            void* __restrict__ outp,
                                            long m0, long n0, unsigned short* smem) {
  const int t = threadIdx.x;
  const int w = t >> 6, l = t & 63;
  const int wr = w >> 1, wc = w & 1;
  const int lr = l & 15, lg = l >> 4;
  // B staging: 4 chunks(16B)/row, 4 lanes/row, 64 rows per glds; src chunk XOR (row>>1)&3
  const int srow = t >> 2;
  const int sxor = ((t & 3) ^ ((t >> 3) & 3)) * 8;
  const unsigned short* gB = Bt + (n0 + srow) * (long)LDB + sxor;

  auto stageB = [&](int c, int kt) {  // 2 glds issues: 8KB
    unsigned short* Bc = smem + c * 4096;
#pragma unroll
    for (int j = 0; j < 2; ++j)
      GLDS16(gB + (long)(64 * j) * LDB + kt * 32, Bc + (64 * j + 16 * w) * 32);
  };

  // A fragment base: lane reads 16B at row (m0+64wr+16i+lr), col (kt*32 + 8lg)
  const unsigned short* gA = A + (m0 + 64 * wr + lr) * (long)LDA + 8 * lg;

  f32x4 acc[4][4] = {};
  short8 af[2][4];
  constexpr int NT = K / 32;  // 16

  // prologue: A(0) first, then B slots 0,1; VMC(2) drains A(0)+B(0), leaves B(1)
#pragma unroll
  for (int i = 0; i < 4; ++i)
    af[0][i] = *(const short8*)&gA[(long)(16 * i) * LDA];
  SB0;
  stageB(0, 0); stageB(1, 1);
  VMC(2);
  BAR8;

#pragma unroll
  for (int kt = 0; kt < NT; ++kt) {
    const int cur = kt & 1, nxt = cur ^ 1;
    if (kt + 1 < NT) {
#pragma unroll
      for (int i = 0; i < 4; ++i)
        af[nxt][i] = *(const short8*)&gA[(long)(16 * i) * LDA + (kt + 1) * 32];
    }
    SB0;
    if (kt + 2 < NT) stageB((kt + 2) % 3, kt + 2);
    SB0;
    const unsigned short* Bc = smem + (kt % 3) * 4096;
    const int kc = (lg ^ ((lr >> 1) & 3)) * 8;
    short8 bfr[4];
#pragma unroll
    for (int i = 0; i < 4; ++i)
      bfr[i] = *(const short8*)&Bc[(64 * wc + 16 * i + lr) * 32 + kc];
#pragma unroll
    for (int mi = 0; mi < 4; ++mi)
#pragma unroll
      for (int ni = 0; ni < 4; ++ni)
        acc[mi][ni] = __builtin_amdgcn_mfma_f32_16x16x32_bf16(af[cur][mi], bfr[ni],
                                                              acc[mi][ni], 0, 0, 0);
    if (kt + 2 < NT) { VMC(2); BAR8; }
    else if (kt + 1 < NT) { VMC(0); BAR8; }
  }
  BAR8;  // last slot's reads done in all waves before patch overwrites the ring

  // bf16 single-pass epilogue via [128][128] XOR-chunked patch (32KB)
  unsigned short* patch = smem;
  float rsum[4][4] = {};
#pragma unroll
  for (int mi = 0; mi < 4; ++mi)
#pragma unroll
    for (int ni = 0; ni < 4; ++ni)
#pragma unroll
      for (int r = 0; r < 4; ++r) {
        const int m = 64 * wr + 16 * mi + 4 * lg + r;
        const int n = 64 * wc + 16 * ni + lr;
        float a = acc[mi][ni][r];
        unsigned short ob;
        if (EPI == 6) ob = f2bf(a);
        else {
          float p = exp2f(a * 0.06375872f);  // (1/sqrt(512))*log2(e)
          ob = f2bf(p);
          rsum[mi][r] += __uint_as_float((unsigned)ob << 16);  // sum what PVF will see
        }
        patch[m * 128 + ((n >> 3) ^ (m & 15)) * 8 + (n & 7)] = ob;
      }
  __syncthreads();
  unsigned short* O = (unsigned short*)outp;
  const int q = t & 3;
#pragma unroll
  for (int p = 0; p < 2; ++p) {
    const int m = 64 * p + (t >> 2);
#pragma unroll
    for (int i = 0; i < 4; ++i) {
      const int cc = i * 4 + q;  // 4 consecutive lanes -> 64B line
      short8 x = *(short8*)&patch[m * 128 + ((cc ^ (m & 15)) * 8)];
      *(short8*)&O[(m0 + m) * LDO + n0 + cc * 8] = x;
    }
  }
  if (EPI == 2) {
#pragma unroll
    for (int off = 1; off < 16; off <<= 1)
#pragma unroll
      for (int mi = 0; mi < 4; ++mi)
#pragma unroll
        for (int r = 0; r < 4; ++r) rsum[mi][r] += __shfl_xor(rsum[mi][r], off);
    if (lr == 0) {
#pragma unroll
      for (int mi = 0; mi < 4; ++mi)
#pragma unroll
        for (int r = 0; r < 4; ++r)
          atomicAdd(&rowsum[m0 + 64 * wr + 16 * mi + 4 * lg + r], rsum[mi][r]);
    }
  }
}

// ---------------- qkvf: P=exp(QK^T/s)+rowsum [y<16] and VFt=WtF.V^T [y>=16] ----------------
__global__ __launch_bounds__(256) void qkvf_kernel(const unsigned short* __restrict__ Qb,
                                                   const unsigned short* __restrict__ KVb,
                                                   const unsigned short* __restrict__ WtF,
                                                   float* __restrict__ rowsum,
                                                   unsigned short* __restrict__ Pbuf,
                                                   unsigned short* __restrict__ VFt) {
  __shared__ __attribute__((aligned(16))) unsigned short smem[16384];  // 32KB (ring 24KB / patch 32KB)
  const int bz = blockIdx.z;
  if (blockIdx.y < 16) {
    gemm_body32<2, CH, 1024, SEQ, CH>(
        Qb + (long)bz * SEQ * CH, KVb + (long)bz * SEQ * 1024,
        rowsum + (long)bz * SEQ, Pbuf + (long)bz * SEQ * SEQ,
        (long)blockIdx.y * 128, (long)blockIdx.x * 128, smem);
  } else {
    gemm_body32<6, CH, 1024, SEQ, CH>(
        WtF, KVb + 512 + (long)bz * SEQ * 1024, nullptr,
        VFt + (long)bz * CH * SEQ,
        (long)(blockIdx.y - 16) * 128, (long)blockIdx.x * 128, smem);
  }
}

// ---------------- pvf: 256Mx128N 8-wave deep-K schedule, 3-buffer LDS ring ----------------
// out = relu(inv[m]*(P.VFt^T) + FC_b) -> fp32.  K=2048 (32 K-tiles of 64).
__global__ __launch_bounds__(512, 2) void pvf_kernel(const unsigned short* __restrict__ Pbuf,
                                                     const unsigned short* __restrict__ VFt,
                                                     const float* __restrict__ FC_b,
                                                     float* __restrict__ rowsum,
                                                     float* __restrict__ out) {
  // 3 ring buffers x (A [256][64] 32KB + B [128][64] 16KB) = 144KB
  __shared__ __attribute__((aligned(16))) unsigned short smem[3][24576];
  const int s = blockIdx.x;            // 0..255
  const int xcd = s & 7, j = s >> 3;   // j 0..31
  const int x = j & 3, pg = j >> 2;    // x 0..3, pg 0..7
  const int y = xcd, bz = pg;
  const long m0 = (long)y * 256, n0 = (long)x * 128;

  const unsigned short* A  = Pbuf + (long)bz * SEQ * SEQ;   // [2048 q][2048 k]
  const unsigned short* Bt = VFt + (long)bz * CH * SEQ;     // [512 e][2048 k]
  constexpr int LDA = SEQ, LDB = SEQ;
  constexpr int NT = SEQ / 64;  // 32 K-tiles

  const int t = threadIdx.x;
  const int w = t >> 6, l = t & 63;
  const int wr = w >> 1, wc = w & 1;   // 4x2 wave grid; per-wave out 64x64
  const int lr = l & 15, lg = l >> 4;

  const int srow = t >> 3;                          // 0..63
  const int schk = ((t & 7) ^ ((t >> 3) & 7)) * 8;
  const unsigned short* gA = A + (m0 + srow) * (long)LDA + schk;
  const unsigned short* gB = Bt + (n0 + srow) * (long)LDB + schk;

  auto stageA = [&](int c, int kt) {  // 256 rows = 4 glds issues
#pragma unroll
    for (int jj = 0; jj < 4; ++jj) {
      unsigned short* d = &smem[c][(64 * jj + 8 * w) * 64];
      GLDS16(gA + (long)(64 * jj) * LDA + (long)kt * 64, d);
    }
  };
  auto stageB = [&](int c, int kt) {  // 128 rows = 2 glds issues
#pragma unroll
    for (int jj = 0; jj < 2; ++jj) {
      unsigned short* d = &smem[c][16384 + (64 * jj + 8 * w) * 64];
      GLDS16(gB + (long)(64 * jj) * LDB + (long)kt * 64, d);
    }
  };

  const int kx0 = (lg ^ (lr & 7)) * 8;        // row&7 == lr&7 for all frag rows
  const int kx1 = ((4 + lg) ^ (lr & 7)) * 8;
  short8 af[8], bf0[4], bf1[4];
  f32x4 acc[4][4] = {};

  auto readA = [&](int c) {  // 8 x ds_read_b128 (4 m-frags x 2 k-halves)
#pragma unroll
    for (int i = 0; i < 4; ++i) {
      const unsigned short* p = &smem[c][(64 * wr + 16 * i + lr) * 64];
      af[2 * i]     = *(const short8*)&p[kx0];
      af[2 * i + 1] = *(const short8*)&p[kx1];
    }
  };
  auto readB = [&](int c, int nh, short8* bf) {  // 4 x ds_read_b128 (2 n-frags x 2 k)
#pragma unroll
    for (int i = 0; i < 2; ++i) {
      const unsigned short* p = &smem[c][16384 + (64 * wc + 16 * (2 * nh + i) + lr) * 64];
      bf[2 * i]     = *(const short8*)&p[kx0];
      bf[2 * i + 1] = *(const short8*)&p[kx1];
    }
  };
  auto quad = [&](int nh, const short8* bf) {  // 16 MFMA: 4 m-frags x 2 n-frags x K=64
    __builtin_amdgcn_s_setprio(1);
#pragma unroll
    for (int mi = 0; mi < 4; ++mi)
#pragma unroll
      for (int jj = 0; jj < 2; ++jj) {
        acc[mi][2 * nh + jj] = __builtin_amdgcn_mfma_f32_16x16x32_bf16(
            af[2 * mi], bf[2 * jj], acc[mi][2 * nh + jj], 0, 0, 0);
        acc[mi][2 * nh + jj] = __builtin_amdgcn_mfma_f32_16x16x32_bf16(
            af[2 * mi + 1], bf[2 * jj + 1], acc[mi][2 * nh + jj], 0, 0, 0);
      }
    __builtin_amdgcn_s_setprio(0);
  };

  // prologue: stage tiles 0 and 1; wait tile 0 (leave tile 1's 6 in flight)
  stageA(0, 0); stageB(0, 0);
  stageA(1, 1); stageB(1, 1);
  VMC(6);
  BAR8;

#pragma unroll
  for (int kt = 0; kt < NT; ++kt) {
    const int b = kt % 3, nb = (kt + 2) % 3;
    const bool st = (kt + 2) < NT;
    // ph_a: reads 12 | stage A(t+2) | quad(nh0)
    readA(b); readB(b, 0, bf0);
    if (st) stageA(nb, kt + 2);
    BAR8; LGKM0; quad(0, bf0); BAR8;
    // ph_b: reads 4 | stage B(t+2) | counted wait | quad(nh1)
    readB(b, 1, bf1);
    if (st) { stageB(nb, kt + 2); VMC(6); } else { VMC(0); }
    BAR8; LGKM0; quad(1, bf1); BAR8;
  }

  // epilogue: relu(acc*inv[m] + bias[n]) -> fp32 via [256][128] f32 XOR-chunked patch
  __syncthreads();
  float* patchF = (float*)&smem[0][0];   // 128KB <= 144KB
  float bv[4];
#pragma unroll
  for (int ni = 0; ni < 4; ++ni) bv[ni] = FC_b[n0 + 64 * wc + 16 * ni + lr];
  float inv[4][4];
#pragma unroll
  for (int mi = 0; mi < 4; ++mi)
#pragma unroll
    for (int r = 0; r < 4; ++r)
      inv[mi][r] = 1.0f / rowsum[(long)bz * SEQ + m0 + 64 * wr + 16 * mi + 4 * lg + r];
#pragma unroll
  for (int mi = 0; mi < 4; ++mi)
#pragma unroll
    for (int ni = 0; ni < 4; ++ni)
#pragma unroll
      for (int r = 0; r < 4; ++r) {
        const int m = 64 * wr + 16 * mi + 4 * lg + r;   // 0..255
        const int n = 64 * wc + 16 * ni + lr;           // 0..127
        patchF[m * 128 + ((n >> 2) ^ (m & 31)) * 4 + (n & 3)] =
            fmaxf(acc[mi][ni][r] * inv[mi][r] + bv[ni], 0.0f);
      }
  __syncthreads();
  {
    float* O = out + (long)bz * SEQ * CH;
    const int q = t & 3, mr = t >> 2;  // q 0..3, mr 0..127
#pragma unroll
    for (int p2 = 0; p2 < 2; ++p2) {
      const int m = 128 * p2 + mr;
#pragma unroll
      for (int i = 0; i < 8; ++i) {
        const int cc = i * 4 + q;  // 4 consecutive lanes -> 64B line
        f32x4 v = *(f32x4*)&patchF[m * 128 + ((cc ^ (m & 31)) * 4)];
        *(f32x4*)&O[(m0 + m) * CH + n0 + cc * 4] = v;
      }
    }
  }
}

extern "C" void kernel_launch(void* const* d_in, const int* in_sizes, int n_in,
                              void* d_out, int out_size, void* d_ws, size_t ws_size,
                              hipStream_t stream) {
  const float* rep  = (const float*)d_in[0];
  const float* rep1 = (const float*)d_in[1];
  const float* Wq_w = (const float*)d_in[2];
  const float* Wq_b = (const float*)d_in[3];
  const float* Wk_w = (const float*)d_in[4];
  const float* Wk_b = (const float*)d_in[5];
  const float* Wv_w = (const float*)d_in[6];
  const float* Wv_b = (const float*)d_in[7];
  const float* FC_w = (const float*)d_in[8];
  const float* FC_b = (const float*)d_in[9];
  float* out = (float*)d_out;
  char* ws = (char*)d_ws;

  const size_t MB = 1024 * 1024;
  // layout: Qb 16MB | KVb 32MB | VFt 16MB | Wt 2MB | biasKV 4KB(+pad) | Pbuf 64MB | rowsum 64KB
  unsigned short* Qb     = (unsigned short*)(ws + 0 * MB);
  unsigned short* KVb    = (unsigned short*)(ws + 16 * MB);
  unsigned short* VFt    = (unsigned short*)(ws + 48 * MB);  // [b][e 512][key 2048]
  unsigned short* Wt4    = (unsigned short*)(ws + 64 * MB);  // WtQ|WtK|WtV|WtF
  float*          biasKV = (float*)(ws + 66 * MB);
  unsigned short* Pbuf   = (unsigned short*)(ws + 67 * MB);
  float*          rowsum = (float*)(ws + 131 * MB);
  const size_t need = 132 * MB;
  if (ws_size < need) return;  // visible failure rather than OOB scribble

  unsigned short* WtF = Wt4 + 3 * 512 * 512;

  // wtrans + biasKV + rowsum-zero (tiny)
  prep2_kernel<<<273, 256, 0, stream>>>(Wq_w, Wk_w, Wv_w, FC_w, Wt4, Wk_b, Wv_b,
                                        biasKV, rowsum);

  // Q/KV projections straight from fp32 activations (ring-3, XCD-grouped)
  proj_kernel<<<1536, 256, 0, stream>>>(rep, rep1, Wt4, Wq_b, biasKV, Qb, KVb);

  // P = exp(QK^T/sqrt(C)) + rowsums  ||  VFt = (V.FC)^T  (A-direct regs + B ring-3; 3D grid)
  qkvf_kernel<<<dim3(16, 20, 8), 256, 0, stream>>>(Qb, KVb, WtF, rowsum, Pbuf, VFt);

  // out = relu(inv[m] * (P.VF) + FC_b)   (256x128 deep-K 3-ring schedule, 256 blocks)
  pvf_kernel<<<256, 512, 0, stream>>>(Pbuf, VFt, FC_b, rowsum, out);
}

// Round 7
// 279.576 us; speedup vs baseline: 1.1710x; 1.1710x over previous
//
#include <hip/hip_runtime.h>

// Fused attention block: q/k/v = relu(X W + b); A = softmax(qk^T/sqrt(C)); out = relu((A v) FC + b)
// B=8, Lq=Lk=2048, C1=C=512.  bf16 16x16x32 MFMA, fp32 accumulate.
// R12->R14: A-direct-to-reg REVERTED (uncoalesced 16B/lane @ 1024B stride -> 64 lines/
// wave-load, 77->124us).  qkvf restored to the R10 ring-3 LDS structure (A+B staged,
// 16KB/slot, stage t+2 early, counted VMC(4), 1 barrier/iter) but WITH the R11 swizzle
// fix (chunk ^= (row>>1)&3 -> 2-way free; R10's row&3 was 4-way) and the proven 3D grid.
// This is the first measurement of {ring-3 + fixed swizzle + 3D grid} together.
// proj (ring-3 + XCD-grouped) / pvf / prep2 unchanged.

typedef __attribute__((ext_vector_type(8))) short short8;  // 8 bf16 (4 VGPRs)
typedef __attribute__((ext_vector_type(4))) float f32x4;

#define SEQ 2048
#define CH 512
#define NB 8
#define MTOT (NB * SEQ)   // 16384

// async global->LDS, 16B/lane; LDS dest = wave-uniform base + lane*16 (m104/m108)
#define GLDS16(gp, lp)                                                                  \
  __builtin_amdgcn_global_load_lds((const __attribute__((address_space(1))) void*)(gp), \
                                   (__attribute__((address_space(3))) void*)(lp), 16, 0, 0)

__device__ __forceinline__ unsigned short f2bf(float f) {  // fp32 -> bf16 RNE
  unsigned u = __float_as_uint(f);
  u += 0x7fffu + ((u >> 16) & 1u);
  return (unsigned short)(u >> 16);
}

// pack two fp32 -> (bf16(hi)<<16)|bf16(lo) by truncation: one v_perm_b32
__device__ __forceinline__ unsigned pack2bf(float lo, float hi) {
  return __builtin_amdgcn_perm(__float_as_uint(hi), __float_as_uint(lo), 0x07060302u);
}

#define CFENCE asm volatile("" ::: "memory")
#define SB0 __builtin_amdgcn_sched_barrier(0)
#define BAR8                          \
  do {                                \
    CFENCE;                           \
    __builtin_amdgcn_s_barrier();     \
    SB0;                              \
  } while (0)
#define VMC(n)                                              \
  do {                                                      \
    asm volatile("s_waitcnt vmcnt(" #n ")" ::: "memory");   \
    SB0;                                                    \
  } while (0)
#define LGKM0                                            \
  do {                                                   \
    asm volatile("s_waitcnt lgkmcnt(0)" ::: "memory");   \
    SB0;                                                 \
  } while (0)

// ---------------- prep2: wtrans x4 + biasKV + rowsum zero (273 blocks) ----------------
__global__ __launch_bounds__(256) void prep2_kernel(
    const float* __restrict__ W0, const float* __restrict__ W1,
    const float* __restrict__ W2, const float* __restrict__ W3,
    unsigned short* __restrict__ Wt,
    const float* __restrict__ Wk_b, const float* __restrict__ Wv_b,
    float* __restrict__ biasKV, float* __restrict__ rowsum) {
  __shared__ __attribute__((aligned(16))) unsigned short tile[64 * 72];
  const int blk = blockIdx.x;
  const int t = threadIdx.x;
  if (blk < 256) {
    const int z = blk >> 6;
    const int bx = blk & 7, by = (blk >> 3) & 7;
    const float* W = (z == 0) ? W0 : (z == 1) ? W1 : (z == 2) ? W2 : W3;
    unsigned short* Wtz = Wt + (long)z * 512 * 512;
    const int k0 = by * 64, n0 = bx * 64;
    const int r = t >> 4, cq = (t & 15) * 4;
#pragma unroll
    for (int j = 0; j < 4; ++j) {
      int row = r + 16 * j;  // k index
      float4 v = *(const float4*)&W[(long)(k0 + row) * 512 + n0 + cq];
      tile[row * 72 + cq + 0] = f2bf(v.x);
      tile[row * 72 + cq + 1] = f2bf(v.y);
      tile[row * 72 + cq + 2] = f2bf(v.z);
      tile[row * 72 + cq + 3] = f2bf(v.w);
    }
    __syncthreads();
#pragma unroll
    for (int j = 0; j < 4; ++j) {
      int row = r + 16 * j;  // n index
      ushort4 o;
      o.x = tile[(cq + 0) * 72 + row];
      o.y = tile[(cq + 1) * 72 + row];
      o.z = tile[(cq + 2) * 72 + row];
      o.w = tile[(cq + 3) * 72 + row];
      *(ushort4*)&Wtz[(long)(n0 + row) * 512 + k0 + cq] = o;
    }
  } else if (blk == 256) {
    biasKV[t] = Wk_b[t];
    biasKV[t + 256] = Wk_b[t + 256];
    biasKV[t + 512] = Wv_b[t];
    biasKV[t + 768] = Wv_b[t + 256];
  } else {
    const int zb = blk - 257;  // 0..15
    f32x4 z4 = {0.f, 0.f, 0.f, 0.f};
    *(f32x4*)&rowsum[(zb * 256 + t) * 4] = z4;
  }
}

// ---------------- proj body: A fp32 [M][512], Bt bf16 [N][512], 128x128 tile, BK=32 ----
// out = relu(A.Bt^T + bias) -> bf16.  3-slot ring (24KB/slot, 72KB), stage t+2 early,
// vmcnt(6) counted, 1 barrier/iter.
template <int LDO>
__device__ __forceinline__ void proj_body(const float* __restrict__ A,
                                          const unsigned short* __restrict__ Bt,
                                          const float* __restrict__ bias,
                                          unsigned short* __restrict__ Op,
                                          long m0, long n0, unsigned short* smem) {
  const int t = threadIdx.x;
  const int w = t >> 6, l = t & 63;
  const int wr = w >> 1, wc = w & 1;
  const int lr = l & 15, lg = l >> 4;
  // A staging: 8 lanes/row (4 floats each), src chunk = (l&7)^(l>>3) [= c0 ^ row&7]
  const float* ga = A + (m0 + 32 * w + (l >> 3)) * CH + ((l & 7) ^ (l >> 3)) * 4;
  // B staging: 4 lanes/row (8 bf16 each), src chunk = (l&3)^((l>>3)&3) [= c0 ^ (row>>1)&3]
  const unsigned short* gb =
      Bt + (n0 + 32 * w + (l >> 2)) * CH + (((l & 3) ^ ((l >> 3) & 3)) * 8);

  auto stage = [&](int c, int kt) {  // 6 glds issues: A 16KB + B 8KB
    float* Ac = (float*)(smem + (long)c * 12288);
    unsigned short* Bc = smem + (long)c * 12288 + 8192;
#pragma unroll
    for (int j = 0; j < 4; ++j)
      GLDS16(ga + (long)8 * j * CH + kt * 32, Ac + (32 * w + 8 * j) * 32);
    GLDS16(gb + kt * 32, Bc + 32 * w * 32);
    GLDS16(gb + (long)16 * CH + kt * 32, Bc + (32 * w + 16) * 32);
  };

  f32x4 acc[4][4] = {};
  constexpr int NT = CH / 32;  // 16
  stage(0, 0); stage(1, 1);
  VMC(6);
  BAR8;
#pragma unroll
  for (int kt = 0; kt < NT; ++kt) {
    const int c = kt % 3;
    if (kt + 2 < NT) stage((kt + 2) % 3, kt + 2);
    const float* Ac = (const float*)(smem + (long)c * 12288);
    const unsigned short* Bc = smem + (long)c * 12288 + 8192;
    short8 af[4], bfr[4];
#pragma unroll
    for (int i = 0; i < 4; ++i) {
      const int row = 64 * wr + 16 * i + lr;
      f32x4 a0 = *(f32x4*)&Ac[row * 32 + ((2 * lg) ^ (lr & 7)) * 4];
      f32x4 a1 = *(f32x4*)&Ac[row * 32 + ((2 * lg + 1) ^ (lr & 7)) * 4];
      union { unsigned u[4]; short8 s; } pk;
      pk.u[0] = pack2bf(a0[0], a0[1]);
      pk.u[1] = pack2bf(a0[2], a0[3]);
      pk.u[2] = pack2bf(a1[0], a1[1]);
      pk.u[3] = pack2bf(a1[2], a1[3]);
      af[i] = pk.s;
      bfr[i] = *(short8*)&Bc[(64 * wc + 16 * i + lr) * 32 + (lg ^ ((lr >> 1) & 3)) * 8];
    }
#pragma unroll
    for (int mi = 0; mi < 4; ++mi)
#pragma unroll
      for (int ni = 0; ni < 4; ++ni)
        acc[mi][ni] =
            __builtin_amdgcn_mfma_f32_16x16x32_bf16(af[mi], bfr[ni], acc[mi][ni], 0, 0, 0);
    if (kt + 2 < NT) { VMC(6); } else if (kt + 1 < NT) { VMC(0); }
    BAR8;
  }
  // epilogue: relu(+bias) -> bf16 via [128][128] XOR-chunked patch (32KB)
  unsigned short* patch = smem;
  float bv[4];
#pragma unroll
  for (int ni = 0; ni < 4; ++ni) bv[ni] = bias[n0 + 64 * wc + 16 * ni + lr];
#pragma unroll
  for (int mi = 0; mi < 4; ++mi)
#pragma unroll
    for (int ni = 0; ni < 4; ++ni)
#pragma unroll
      for (int r = 0; r < 4; ++r) {
        const int m = 64 * wr + 16 * mi + 4 * lg + r;
        const int n = 64 * wc + 16 * ni + lr;
        patch[m * 128 + ((n >> 3) ^ (m & 15)) * 8 + (n & 7)] =
            f2bf(fmaxf(acc[mi][ni][r] + bv[ni], 0.0f));
      }
  __syncthreads();
  const int q = t & 3;
#pragma unroll
  for (int p = 0; p < 2; ++p) {
    const int m = 64 * p + (t >> 2);
#pragma unroll
    for (int i = 0; i < 4; ++i) {
      const int cc = i * 4 + q;  // 4 consecutive lanes -> 64B line
      short8 x = *(short8*)&patch[m * 128 + ((cc ^ (m & 15)) * 8)];
      *(short8*)&Op[(m0 + m) * LDO + n0 + cc * 8] = x;
    }
  }
}

// Q = relu(rep Wq + b) [x<4]; KV = relu(rep1 [Wk|Wv] + b) [x>=4]
// 1D grid 1536, XCD-grouped: xcd = bid&7 owns 16 m-panels; the 12 n-blocks of one
// m-panel are spaced 8 apart in bid -> same XCD, co-dispatched.
__global__ __launch_bounds__(256) void proj_kernel(const float* __restrict__ rep,
                                                   const float* __restrict__ rep1,
                                                   const unsigned short* __restrict__ Wt,
                                                   const float* __restrict__ Wq_b,
                                                   const float* __restrict__ biasKV,
                                                   unsigned short* __restrict__ Qb,
                                                   unsigned short* __restrict__ KVb) {
  __shared__ __attribute__((aligned(16))) unsigned short smem[36864];  // 72KB (3x24KB ring)
  const int bid = blockIdx.x;
  const int xcd = bid & 7, j = bid >> 3;   // j 0..191
  const int mp = j / 12, x = j % 12;       // mp 0..15
  const long m0 = (long)(xcd * 16 + mp) * 128;
  if (x < 4)
    proj_body<CH>(rep, Wt, Wq_b, Qb, m0, (long)x * 128, smem);
  else
    proj_body<1024>(rep1, Wt + 512 * 512, biasKV, KVb, m0, (long)(x - 4) * 128, smem);
}

// ---------------- qkvf NT GEMM body, 128x128 tile, BK=32, 3-slot ring (A+B LDS) ------
// EPI 6: acc -> bf16                        (VFt)
// EPI 2: exp2(acc*scale) -> bf16 P, rowsum[m] += sum_n p   (QK^T)
// Ring: slot = 16KB (A 8KB + B 8KB), 3 slots = 48KB (3 blocks/CU).  Stage slot t+2 at
// top of iter t (4 glds), read frags slot t, 16 MFMA, VMC(4) (slot t+1 landed),
// ONE barrier.  Swizzle: chunk' = chunk ^ ((row>>1)&3) -> bank = 16*(row&1)+4*chunk'
// has period 8 over a 16-lane group = 2 lanes/bank = free (m136).
template <int EPI, int LDA, int LDB, int LDO, int K>
__device__ __forceinline__ void gemm_body32(const unsigned short* __restrict__ A,
                                            const unsigned short* __restrict__ Bt,
                                            float* __restrict__ rowsum,
                                            void* __restrict__ outp,
                                            long m0, long n0, unsigned short* smem) {
  const int t = threadIdx.x;
  const int w = t >> 6, l = t & 63;
  const int wr = w >> 1, wc = w & 1;
  const int lr = l & 15, lg = l >> 4;
  // staging: 4 chunks(16B)/row, 4 lanes/row, 64 rows per glds; src chunk XOR (row>>1)&3
  const int srow = t >> 2;                       // 0..63 (= 16w + l>>2)
  const int sxor = ((t & 3) ^ ((t >> 3) & 3)) * 8;
  const unsigned short* gA = A + (m0 + srow) * (long)LDA + sxor;
  const unsigned short* gB = Bt + (n0 + srow) * (long)LDB + sxor;

  auto stage = [&](int c, int kt) {  // 4 glds issues: A 8KB + B 8KB
    unsigned short* Ac = smem + c * 8192;
    unsigned short* Bc = Ac + 4096;
#pragma unroll
    for (int j = 0; j < 2; ++j) {
      GLDS16(gA + (long)(64 * j) * LDA + kt * 32, Ac + (64 * j + 16 * w) * 32);
      GLDS16(gB + (long)(64 * j) * LDB + kt * 32, Bc + (64 * j + 16 * w) * 32);
    }
  };

  f32x4 acc[4][4] = {};
  constexpr int NT = K / 32;  // 16
  stage(0, 0); stage(1, 1);
  VMC(4);
  BAR8;
#pragma unroll
  for (int kt = 0; kt < NT; ++kt) {
    const int c = kt % 3;
    if (kt + 2 < NT) stage((kt + 2) % 3, kt + 2);
    const unsigned short* Ac = smem + c * 8192;
    const unsigned short* Bc = Ac + 4096;
    short8 af[4], bfr[4];
    const int kc = (lg ^ ((lr >> 1) & 3)) * 8;
#pragma unroll
    for (int i = 0; i < 4; ++i) {
      af[i]  = *(const short8*)&Ac[(64 * wr + 16 * i + lr) * 32 + kc];
      bfr[i] = *(const short8*)&Bc[(64 * wc + 16 * i + lr) * 32 + kc];
    }
#pragma unroll
    for (int mi = 0; mi < 4; ++mi)
#pragma unroll
      for (int ni = 0; ni < 4; ++ni)
        acc[mi][ni] =
            __builtin_amdgcn_mfma_f32_16x16x32_bf16(af[mi], bfr[ni], acc[mi][ni], 0, 0, 0);
    if (kt + 2 < NT) { VMC(4); } else if (kt + 1 < NT) { VMC(0); }
    BAR8;
  }

  // bf16 single-pass epilogue via [128][128] XOR-chunked patch (32KB)
  unsigned short* patch = smem;
  float rsum[4][4] = {};
#pragma unroll
  for (int mi = 0; mi < 4; ++mi)
#pragma unroll
    for (int ni = 0; ni < 4; ++ni)
#pragma unroll
      for (int r = 0; r < 4; ++r) {
        const int m = 64 * wr + 16 * mi + 4 * lg + r;
        const int n = 64 * wc + 16 * ni + lr;
        float a = acc[mi][ni][r];
        unsigned short ob;
        if (EPI == 6) ob = f2bf(a);
        else {
          float p = exp2f(a * 0.06375872f);  // (1/sqrt(512))*log2(e)
          ob = f2bf(p);
          rsum[mi][r] += __uint_as_float((unsigned)ob << 16);  // sum what PVF will see
        }
        patch[m * 128 + ((n >> 3) ^ (m & 15)) * 8 + (n & 7)] = ob;
      }
  __syncthreads();
  unsigned short* O = (unsigned short*)outp;
  const int q = t & 3;
#pragma unroll
  for (int p = 0; p < 2; ++p) {
    const int m = 64 * p + (t >> 2);
#pragma unroll
    for (int i = 0; i < 4; ++i) {
      const int cc = i * 4 + q;  // 4 consecutive lanes -> 64B line
      short8 x = *(short8*)&patch[m * 128 + ((cc ^ (m & 15)) * 8)];
      *(short8*)&O[(m0 + m) * LDO + n0 + cc * 8] = x;
    }
  }
  if (EPI == 2) {
#pragma unroll
    for (int off = 1; off < 16; off <<= 1)
#pragma unroll
      for (int mi = 0; mi < 4; ++mi)
#pragma unroll
        for (int r = 0; r < 4; ++r) rsum[mi][r] += __shfl_xor(rsum[mi][r], off);
    if (lr == 0) {
#pragma unroll
      for (int mi = 0; mi < 4; ++mi)
#pragma unroll
        for (int r = 0; r < 4; ++r)
          atomicAdd(&rowsum[m0 + 64 * wr + 16 * mi + 4 * lg + r], rsum[mi][r]);
    }
  }
}

// ---------------- qkvf: P=exp(QK^T/s)+rowsum [y<16] and VFt=WtF.V^T [y>=16] ----------------
__global__ __launch_bounds__(256) void qkvf_kernel(const unsigned short* __restrict__ Qb,
                                                   const unsigned short* __restrict__ KVb,
                                                   const unsigned short* __restrict__ WtF,
                                                   float* __restrict__ rowsum,
                                                   unsigned short* __restrict__ Pbuf,
                                                   unsigned short* __restrict__ VFt) {
  __shared__ __attribute__((aligned(16))) unsigned short smem[3 * 8192];  // 48KB ring
  const int bz = blockIdx.z;
  if (blockIdx.y < 16) {
    gemm_body32<2, CH, 1024, SEQ, CH>(
        Qb + (long)bz * SEQ * CH, KVb + (long)bz * SEQ * 1024,
        rowsum + (long)bz * SEQ, Pbuf + (long)bz * SEQ * SEQ,
        (long)blockIdx.y * 128, (long)blockIdx.x * 128, smem);
  } else {
    gemm_body32<6, CH, 1024, SEQ, CH>(
        WtF, KVb + 512 + (long)bz * SEQ * 1024, nullptr,
        VFt + (long)bz * CH * SEQ,
        (long)(blockIdx.y - 16) * 128, (long)blockIdx.x * 128, smem);
  }
}

// ---------------- pvf: 256Mx128N 8-wave deep-K schedule, 3-buffer LDS ring ----------------
// out = relu(inv[m]*(P.VFt^T) + FC_b) -> fp32.  K=2048 (32 K-tiles of 64).
__global__ __launch_bounds__(512, 2) void pvf_kernel(const unsigned short* __restrict__ Pbuf,
                                                     const unsigned short* __restrict__ VFt,
                                                     const float* __restrict__ FC_b,
                                                     float* __restrict__ rowsum,
                                                     float* __restrict__ out) {
  // 3 ring buffers x (A [256][64] 32KB + B [128][64] 16KB) = 144KB
  __shared__ __attribute__((aligned(16))) unsigned short smem[3][24576];
  const int s = blockIdx.x;            // 0..255
  const int xcd = s & 7, j = s >> 3;   // j 0..31
  const int x = j & 3, pg = j >> 2;    // x 0..3, pg 0..7
  const int y = xcd, bz = pg;
  const long m0 = (long)y * 256, n0 = (long)x * 128;

  const unsigned short* A  = Pbuf + (long)bz * SEQ * SEQ;   // [2048 q][2048 k]
  const unsigned short* Bt = VFt + (long)bz * CH * SEQ;     // [512 e][2048 k]
  constexpr int LDA = SEQ, LDB = SEQ;
  constexpr int NT = SEQ / 64;  // 32 K-tiles

  const int t = threadIdx.x;
  const int w = t >> 6, l = t & 63;
  const int wr = w >> 1, wc = w & 1;   // 4x2 wave grid; per-wave out 64x64
  const int lr = l & 15, lg = l >> 4;

  const int srow = t >> 3;                          // 0..63
  const int schk = ((t & 7) ^ ((t >> 3) & 7)) * 8;
  const unsigned short* gA = A + (m0 + srow) * (long)LDA + schk;
  const unsigned short* gB = Bt + (n0 + srow) * (long)LDB + schk;

  auto stageA = [&](int c, int kt) {  // 256 rows = 4 glds issues
#pragma unroll
    for (int jj = 0; jj < 4; ++jj) {
      unsigned short* d = &smem[c][(64 * jj + 8 * w) * 64];
      GLDS16(gA + (long)(64 * jj) * LDA + (long)kt * 64, d);
    }
  };
  auto stageB = [&](int c, int kt) {  // 128 rows = 2 glds issues
#pragma unroll
    for (int jj = 0; jj < 2; ++jj) {
      unsigned short* d = &smem[c][16384 + (64 * jj + 8 * w) * 64];
      GLDS16(gB + (long)(64 * jj) * LDB + (long)kt * 64, d);
    }
  };

  const int kx0 = (lg ^ (lr & 7)) * 8;        // row&7 == lr&7 for all frag rows
  const int kx1 = ((4 + lg) ^ (lr & 7)) * 8;
  short8 af[8], bf0[4], bf1[4];
  f32x4 acc[4][4] = {};

  auto readA = [&](int c) {  // 8 x ds_read_b128 (4 m-frags x 2 k-halves)
#pragma unroll
    for (int i = 0; i < 4; ++i) {
      const unsigned short* p = &smem[c][(64 * wr + 16 * i + lr) * 64];
      af[2 * i]     = *(const short8*)&p[kx0];
      af[2 * i + 1] = *(const short8*)&p[kx1];
    }
  };
  auto readB = [&](int c, int nh, short8* bf) {  // 4 x ds_read_b128 (2 n-frags x 2 k)
#pragma unroll
    for (int i = 0; i < 2; ++i) {
      const unsigned short* p = &smem[c][16384 + (64 * wc + 16 * (2 * nh + i) + lr) * 64];
      bf[2 * i]     = *(const short8*)&p[kx0];
      bf[2 * i + 1] = *(const short8*)&p[kx1];
    }
  };
  auto quad = [&](int nh, const short8* bf) {  // 16 MFMA: 4 m-frags x 2 n-frags x K=64
    __builtin_amdgcn_s_setprio(1);
#pragma unroll
    for (int mi = 0; mi < 4; ++mi)
#pragma unroll
      for (int jj = 0; jj < 2; ++jj) {
        acc[mi][2 * nh + jj] = __builtin_amdgcn_mfma_f32_16x16x32_bf16(
            af[2 * mi], bf[2 * jj], acc[mi][2 * nh + jj], 0, 0, 0);
        acc[mi][2 * nh + jj] = __builtin_amdgcn_mfma_f32_16x16x32_bf16(
            af[2 * mi + 1], bf[2 * jj + 1], acc[mi][2 * nh + jj], 0, 0, 0);
      }
    __builtin_amdgcn_s_setprio(0);
  };

  // prologue: stage tiles 0 and 1; wait tile 0 (leave tile 1's 6 in flight)
  stageA(0, 0); stageB(0, 0);
  stageA(1, 1); stageB(1, 1);
  VMC(6);
  BAR8;

#pragma unroll
  for (int kt = 0; kt < NT; ++kt) {
    const int b = kt % 3, nb = (kt + 2) % 3;
    const bool st = (kt + 2) < NT;
    // ph_a: reads 12 | stage A(t+2) | quad(nh0)
    readA(b); readB(b, 0, bf0);
    if (st) stageA(nb, kt + 2);
    BAR8; LGKM0; quad(0, bf0); BAR8;
    // ph_b: reads 4 | stage B(t+2) | counted wait | quad(nh1)
    readB(b, 1, bf1);
    if (st) { stageB(nb, kt + 2); VMC(6); } else { VMC(0); }
    BAR8; LGKM0; quad(1, bf1); BAR8;
  }

  // epilogue: relu(acc*inv[m] + bias[n]) -> fp32 via [256][128] f32 XOR-chunked patch
  __syncthreads();
  float* patchF = (float*)&smem[0][0];   // 128KB <= 144KB
  float bv[4];
#pragma unroll
  for (int ni = 0; ni < 4; ++ni) bv[ni] = FC_b[n0 + 64 * wc + 16 * ni + lr];
  float inv[4][4];
#pragma unroll
  for (int mi = 0; mi < 4; ++mi)
#pragma unroll
    for (int r = 0; r < 4; ++r)
      inv[mi][r] = 1.0f / rowsum[(long)bz * SEQ + m0 + 64 * wr + 16 * mi + 4 * lg + r];
#pragma unroll
  for (int mi = 0; mi < 4; ++mi)
#pragma unroll
    for (int ni = 0; ni < 4; ++ni)
#pragma unroll
      for (int r = 0; r < 4; ++r) {
        const int m = 64 * wr + 16 * mi + 4 * lg + r;   // 0..255
        const int n = 64 * wc + 16 * ni + lr;           // 0..127
        patchF[m * 128 + ((n >> 2) ^ (m & 31)) * 4 + (n & 3)] =
            fmaxf(acc[mi][ni][r] * inv[mi][r] + bv[ni], 0.0f);
      }
  __syncthreads();
  {
    float* O = out + (long)bz * SEQ * CH;
    const int q = t & 3, mr = t >> 2;  // q 0..3, mr 0..127
#pragma unroll
    for (int p2 = 0; p2 < 2; ++p2) {
      const int m = 128 * p2 + mr;
#pragma unroll
      for (int i = 0; i < 8; ++i) {
        const int cc = i * 4 + q;  // 4 consecutive lanes -> 64B line
        f32x4 v = *(f32x4*)&patchF[m * 128 + ((cc ^ (m & 31)) * 4)];
        *(f32x4*)&O[(m0 + m) * CH + n0 + cc * 4] = v;
      }
    }
  }
}

extern "C" void kernel_launch(void* const* d_in, const int* in_sizes, int n_in,
                              void* d_out, int out_size, void* d_ws, size_t ws_size,
                              hipStream_t stream) {
  const float* rep  = (const float*)d_in[0];
  const float* rep1 = (const float*)d_in[1];
  const float* Wq_w = (const float*)d_in[2];
  const float* Wq_b = (const float*)d_in[3];
  const float* Wk_w = (const float*)d_in[4];
  const float* Wk_b = (const float*)d_in[5];
  const float* Wv_w = (const float*)d_in[6];
  const float* Wv_b = (const float*)d_in[7];
  const float* FC_w = (const float*)d_in[8];
  const float* FC_b = (const float*)d_in[9];
  float* out = (float*)d_out;
  char* ws = (char*)d_ws;

  const size_t MB = 1024 * 1024;
  // layout: Qb 16MB | KVb 32MB | VFt 16MB | Wt 2MB | biasKV 4KB(+pad) | Pbuf 64MB | rowsum 64KB
  unsigned short* Qb     = (unsigned short*)(ws + 0 * MB);
  unsigned short* KVb    = (unsigned short*)(ws + 16 * MB);
  unsigned short* VFt    = (unsigned short*)(ws + 48 * MB);  // [b][e 512][key 2048]
  unsigned short* Wt4    = (unsigned short*)(ws + 64 * MB);  // WtQ|WtK|WtV|WtF
  float*          biasKV = (float*)(ws + 66 * MB);
  unsigned short* Pbuf   = (unsigned short*)(ws + 67 * MB);
  float*          rowsum = (float*)(ws + 131 * MB);
  const size_t need = 132 * MB;
  if (ws_size < need) return;  // visible failure rather than OOB scribble

  unsigned short* WtF = Wt4 + 3 * 512 * 512;

  // wtrans + biasKV + rowsum-zero (tiny)
  prep2_kernel<<<273, 256, 0, stream>>>(Wq_w, Wk_w, Wv_w, FC_w, Wt4, Wk_b, Wv_b,
                                        biasKV, rowsum);

  // Q/KV projections straight from fp32 activations (ring-3, XCD-grouped)
  proj_kernel<<<1536, 256, 0, stream>>>(rep, rep1, Wt4, Wq_b, biasKV, Qb, KVb);

  // P = exp(QK^T/sqrt(C)) + rowsums  ||  VFt = (V.FC)^T  (ring-3 LDS, fixed swizzle, 3D grid)
  qkvf_kernel<<<dim3(16, 20, 8), 256, 0, stream>>>(Qb, KVb, WtF, rowsum, Pbuf, VFt);

  // out = relu(inv[m] * (P.VF) + FC_b)   (256x128 deep-K 3-ring schedule, 256 blocks)
  pvf_kernel<<<256, 512, 0, stream>>>(Pbuf, VFt, FC_b, rowsum, out);
}